// Round 1
// baseline (203.005 us; speedup 1.0000x reference)
//
#include <hip/hip_runtime.h>

// Problem constants (mirrors reference)
#define NI    32              // batch
#define HH    1024
#define WW    1024
#define BHW   16              // pool window
#define BS    14              // block stride
#define NBH   73              // block count h
#define NBW   73              // block count w
#define NCHUNK (NI * NBH)     // 2336 block-rows
#define TOTAL  (NI * NBH * NBW) // 170528

// ---------------------------------------------------------------------------
// Kernel 0: fill output with -1 (reference pads nonzero with fill_value=-1)
// out_size = TOTAL*3 = 511584, divisible by 4 -> int4 stores.
__global__ __launch_bounds__(256) void fill_kernel(int4* __restrict__ out, int n4) {
    int i = blockIdx.x * blockDim.x + threadIdx.x;
    if (i < n4) out[i] = make_int4(-1, -1, -1, -1);
}

// ---------------------------------------------------------------------------
// Kernel 1: one workgroup per (n, by) block-row.
// Separable max: 256 threads each own 4 contiguous columns (float4 loads),
// reduce 16 rows (clipped to [0,H)) -> colmax[1024] in LDS, then threads
// 0..72 take the horizontal 16-wide max (clipped to [0,W)) and emit flag.
__global__ __launch_bounds__(256) void pool_kernel(const float* __restrict__ mask,
                                                   unsigned char* __restrict__ flags,
                                                   int* __restrict__ counts) {
    const int chunk = blockIdx.x;         // n*NBH + by
    const int n  = chunk / NBH;
    const int by = chunk % NBH;
    const int tid = threadIdx.x;

    __shared__ float colmax[WW];
    __shared__ int cnt;
    if (tid == 0) cnt = 0;

    const float* base = mask + (size_t)n * HH * WW;
    const int r0 = by * BS - 1;           // padded window start (pad=1)
    const int c  = tid * 4;               // 4 columns per thread

    float4 m = make_float4(-1e30f, -1e30f, -1e30f, -1e30f);
    #pragma unroll
    for (int dr = 0; dr < BHW; ++dr) {
        const int r = r0 + dr;
        if (r >= 0 && r < HH) {
            const float4 v = *(const float4*)(base + (size_t)r * WW + c);
            m.x = fmaxf(m.x, v.x);
            m.y = fmaxf(m.y, v.y);
            m.z = fmaxf(m.z, v.z);
            m.w = fmaxf(m.w, v.w);
        }
    }
    colmax[c + 0] = m.x;
    colmax[c + 1] = m.y;
    colmax[c + 2] = m.z;
    colmax[c + 3] = m.w;
    __syncthreads();

    if (tid < NBW) {
        const int c0 = tid * BS - 1;
        float mx = -1e30f;
        #pragma unroll
        for (int dc = 0; dc < BHW; ++dc) {
            const int cc = c0 + dc;
            if (cc >= 0 && cc < WW) mx = fmaxf(mx, colmax[cc]);
        }
        const unsigned char f = (mx > 0.9f) ? 1 : 0;
        flags[(size_t)chunk * NBW + tid] = f;
        if (f) atomicAdd(&cnt, 1);
    }
    __syncthreads();
    if (tid == 0) counts[chunk] = cnt;
}

// ---------------------------------------------------------------------------
// Kernel 2: exclusive scan of 2336 per-chunk counts, single workgroup.
__global__ __launch_bounds__(256) void scan_kernel(const int* __restrict__ counts,
                                                   int* __restrict__ offsets) {
    const int tid = threadIdx.x;
    const int SEG = (NCHUNK + 255) / 256;   // 10
    __shared__ int ssum[256];

    int local[(NCHUNK + 255) / 256];
    int s = 0;
    const int b0 = tid * SEG;
    #pragma unroll
    for (int i = 0; i < SEG; ++i) {
        const int idx = b0 + i;
        const int v = (idx < NCHUNK) ? counts[idx] : 0;
        local[i] = v;
        s += v;
    }
    ssum[tid] = s;
    __syncthreads();

    // Hillis-Steele inclusive scan over 256 partial sums
    for (int off = 1; off < 256; off <<= 1) {
        const int v = (tid >= off) ? ssum[tid - off] : 0;
        __syncthreads();
        ssum[tid] += v;
        __syncthreads();
    }

    int run = (tid == 0) ? 0 : ssum[tid - 1];
    #pragma unroll
    for (int i = 0; i < SEG; ++i) {
        const int idx = b0 + i;
        if (idx < NCHUNK) offsets[idx] = run;
        run += local[i];
    }
}

// ---------------------------------------------------------------------------
// Kernel 3: stable scatter. One workgroup per chunk; local prefix within the
// 73-entry row + global chunk offset -> write (n, by, bx) triples.
__global__ __launch_bounds__(128) void scatter_kernel(const unsigned char* __restrict__ flags,
                                                      const int* __restrict__ offsets,
                                                      int* __restrict__ out) {
    const int chunk = blockIdx.x;
    const int n  = chunk / NBH;
    const int by = chunk % NBH;
    const int tid = threadIdx.x;

    __shared__ int sflag[NBW];
    if (tid < NBW) sflag[tid] = flags[(size_t)chunk * NBW + tid];
    __syncthreads();

    if (tid < NBW && sflag[tid]) {
        int p = 0;
        for (int i = 0; i < tid; ++i) p += sflag[i];
        const int pos = offsets[chunk] + p;
        out[3 * pos + 0] = n;
        out[3 * pos + 1] = by;
        out[3 * pos + 2] = tid;
    }
}

// ---------------------------------------------------------------------------
extern "C" void kernel_launch(void* const* d_in, const int* in_sizes, int n_in,
                              void* d_out, int out_size, void* d_ws, size_t ws_size,
                              hipStream_t stream) {
    const float* mask = (const float*)d_in[0];
    int* out = (int*)d_out;

    // workspace layout: [counts: 2336 int][offsets: 2336 int][flags: 170528 u8]
    int* counts  = (int*)d_ws;
    int* offsets = counts + NCHUNK;
    unsigned char* flags = (unsigned char*)(offsets + NCHUNK);

    const int n4 = out_size / 4;  // 511584 / 4 = 127896
    fill_kernel<<<(n4 + 255) / 256, 256, 0, stream>>>((int4*)d_out, n4);
    pool_kernel<<<NCHUNK, 256, 0, stream>>>(mask, flags, counts);
    scan_kernel<<<1, 256, 0, stream>>>(counts, offsets);
    scatter_kernel<<<NCHUNK, 128, 0, stream>>>(flags, offsets, out);
}

// Round 2
// 193.339 us; speedup vs baseline: 1.0500x; 1.0500x over previous
//
#include <hip/hip_runtime.h>

// Problem constants (mirrors reference)
#define NI    32              // batch
#define HH    1024
#define WW    1024
#define BHW   16              // pool window
#define BS    14              // block stride
#define NBH   73              // block count h
#define NBW   73              // block count w
#define NCHUNK (NI * NBH)     // 2336 block-rows
#define TOTAL  (NI * NBH * NBW) // 170528

struct umask2 { unsigned long long x, y; };

// ---------------------------------------------------------------------------
// Kernel 0: fill output with -1 (reference pads nonzero with fill_value=-1).
__global__ __launch_bounds__(256) void fill_kernel(int4* __restrict__ out, int n4) {
    int i = blockIdx.x * blockDim.x + threadIdx.x;
    if (i < n4) out[i] = make_int4(-1, -1, -1, -1);
}

// ---------------------------------------------------------------------------
// Kernel 1: one workgroup per (n, by) block-row.
// Branchless row clamp: only by==0 has an out-of-range row (r=-1); clamping to
// row 0 re-reads a row already in the window -> max unchanged. Upper edge never
// clips (max r = 72*14-1+15 = 1022). Same argument for columns in the
// horizontal pass. Emits a 128-bit active mask + popcount per chunk.
__global__ __launch_bounds__(256) void pool_kernel(const float* __restrict__ mask,
                                                   umask2* __restrict__ masks,
                                                   int* __restrict__ counts) {
    const int chunk = blockIdx.x;         // n*NBH + by
    const int n  = chunk / NBH;
    const int by = chunk % NBH;
    const int tid = threadIdx.x;

    __shared__ float colmax[WW];
    __shared__ unsigned long long sm0, sm1;

    const float* base = mask + (size_t)n * HH * WW;
    const int r0 = by * BS - 1;           // padded window start (pad=1)
    const int c  = tid * 4;               // 4 columns per thread

    float4 m = make_float4(-1e30f, -1e30f, -1e30f, -1e30f);
    #pragma unroll
    for (int dr = 0; dr < BHW; ++dr) {
        const int r = max(r0 + dr, 0);    // branchless clamp (see above)
        const float4 v = *(const float4*)(base + (size_t)r * WW + c);
        m.x = fmaxf(m.x, v.x);
        m.y = fmaxf(m.y, v.y);
        m.z = fmaxf(m.z, v.z);
        m.w = fmaxf(m.w, v.w);
    }
    colmax[c + 0] = m.x;
    colmax[c + 1] = m.y;
    colmax[c + 2] = m.z;
    colmax[c + 3] = m.w;
    __syncthreads();

    int f = 0;
    if (tid < NBW) {
        const int c0 = tid * BS - 1;
        float mx = colmax[max(c0, 0)];    // dc=0 clamped; dc>=1 always >= 0
        #pragma unroll
        for (int dc = 1; dc < BHW; ++dc) mx = fmaxf(mx, colmax[c0 + dc]);
        f = (mx > 0.9f) ? 1 : 0;
    }
    const unsigned long long b = __ballot(f);
    const int wave = tid >> 6;
    const int lane = tid & 63;
    if (wave == 0 && lane == 0) sm0 = b;  // bits for bx 0..63
    if (wave == 1 && lane == 0) sm1 = b;  // bits for bx 64..72
    __syncthreads();
    if (tid == 0) {
        umask2 mm; mm.x = sm0; mm.y = sm1;
        masks[chunk] = mm;
        counts[chunk] = __popcll(sm0) + __popcll(sm1);
    }
}

// ---------------------------------------------------------------------------
// Kernel 2: fused exclusive-scan + stable scatter. One workgroup per chunk;
// the block recomputes its own global offset by summing counts[0..chunk-1]
// (<= 2336 L2-hot ints, ~18 loads/thread), then writes (n, by, bx) triples at
// offset + within-chunk popcount prefix. Row-major stable order preserved.
__global__ __launch_bounds__(128) void scatter_kernel(const umask2* __restrict__ masks,
                                                      const int* __restrict__ counts,
                                                      int* __restrict__ out) {
    const int chunk = blockIdx.x;
    const int n  = chunk / NBH;
    const int by = chunk % NBH;
    const int tid  = threadIdx.x;
    const int lane = tid & 63;
    const int wave = tid >> 6;

    __shared__ int wsum[2];

    // global exclusive prefix of counts
    int partial = 0;
    for (int i = tid; i < chunk; i += 128) partial += counts[i];
    #pragma unroll
    for (int off = 32; off > 0; off >>= 1) partial += __shfl_down(partial, off, 64);
    if (lane == 0) wsum[wave] = partial;

    const umask2 m = masks[chunk];        // broadcast load, L2-hot
    __syncthreads();
    const int baseoff = wsum[0] + wsum[1];

    if (tid < NBW) {
        int f, prefix;
        if (wave == 0) {                  // bx 0..63 (wave-uniform branch)
            f = (int)((m.x >> tid) & 1ull);
            prefix = __popcll(m.x & ((1ull << tid) - 1ull));
        } else {                          // bx 64..72
            const int t = tid - 64;
            f = (int)((m.y >> t) & 1ull);
            prefix = __popcll(m.x) + __popcll(m.y & ((1ull << t) - 1ull));
        }
        if (f) {
            const int pos = baseoff + prefix;
            out[3 * pos + 0] = n;
            out[3 * pos + 1] = by;
            out[3 * pos + 2] = tid;
        }
    }
}

// ---------------------------------------------------------------------------
extern "C" void kernel_launch(void* const* d_in, const int* in_sizes, int n_in,
                              void* d_out, int out_size, void* d_ws, size_t ws_size,
                              hipStream_t stream) {
    const float* mask = (const float*)d_in[0];
    int* out = (int*)d_out;

    // workspace layout: [masks: 2336 x 16B][counts: 2336 x 4B]
    umask2* masks = (umask2*)d_ws;
    int* counts = (int*)(masks + NCHUNK);

    const int n4 = out_size / 4;  // 511584 / 4 = 127896
    fill_kernel<<<(n4 + 255) / 256, 256, 0, stream>>>((int4*)d_out, n4);
    pool_kernel<<<NCHUNK, 256, 0, stream>>>(mask, masks, counts);
    scatter_kernel<<<NCHUNK, 128, 0, stream>>>(masks, counts, out);
}

// Round 3
// 190.817 us; speedup vs baseline: 1.0639x; 1.0132x over previous
//
#include <hip/hip_runtime.h>

// Problem constants (mirrors reference)
#define NI    32              // batch
#define HH    1024
#define WW    1024
#define BHW   16              // pool window
#define BS    14              // block stride
#define NBH   73              // block count h
#define NBW   73              // block count w
#define NCHUNK (NI * NBH)     // 2336 block-rows
#define TOTAL  (NI * NBH * NBW) // 170528

struct umask2 { unsigned long long x, y; };

// ---------------------------------------------------------------------------
// Kernel 1: one workgroup per (n, by) block-row.
// Branchless row clamp: only by==0 has an out-of-range row (r=-1); clamping to
// row 0 re-reads a row already in the window -> max unchanged. Upper edge never
// clips (max r = 72*14-1+15 = 1022). Same for columns in the horizontal pass.
// Emits a 128-bit active mask + popcount per chunk.
__global__ __launch_bounds__(256) void pool_kernel(const float* __restrict__ mask,
                                                   umask2* __restrict__ masks,
                                                   int* __restrict__ counts) {
    const int chunk = blockIdx.x;         // n*NBH + by
    const int n  = chunk / NBH;
    const int by = chunk % NBH;
    const int tid = threadIdx.x;

    __shared__ float colmax[WW];
    __shared__ unsigned long long sm0, sm1;

    const float* base = mask + (size_t)n * HH * WW;
    const int r0 = by * BS - 1;           // padded window start (pad=1)
    const int c  = tid * 4;               // 4 columns per thread

    float4 m = make_float4(-1e30f, -1e30f, -1e30f, -1e30f);
    #pragma unroll
    for (int dr = 0; dr < BHW; ++dr) {
        const int r = max(r0 + dr, 0);    // branchless clamp (see above)
        const float4 v = *(const float4*)(base + (size_t)r * WW + c);
        m.x = fmaxf(m.x, v.x);
        m.y = fmaxf(m.y, v.y);
        m.z = fmaxf(m.z, v.z);
        m.w = fmaxf(m.w, v.w);
    }
    colmax[c + 0] = m.x;
    colmax[c + 1] = m.y;
    colmax[c + 2] = m.z;
    colmax[c + 3] = m.w;
    __syncthreads();

    int f = 0;
    if (tid < NBW) {
        const int c0 = tid * BS - 1;
        float mx = colmax[max(c0, 0)];    // dc=0 clamped; dc>=1 always >= 0
        #pragma unroll
        for (int dc = 1; dc < BHW; ++dc) mx = fmaxf(mx, colmax[c0 + dc]);
        f = (mx > 0.9f) ? 1 : 0;
    }
    const unsigned long long b = __ballot(f);
    const int wave = tid >> 6;
    const int lane = tid & 63;
    if (wave == 0 && lane == 0) sm0 = b;  // bits for bx 0..63
    if (wave == 1 && lane == 0) sm1 = b;  // bits for bx 64..72
    __syncthreads();
    if (tid == 0) {
        umask2 mm; mm.x = sm0; mm.y = sm1;
        masks[chunk] = mm;
        counts[chunk] = __popcll(sm0) + __popcll(sm1);
    }
}

// ---------------------------------------------------------------------------
// Kernel 2: fused exclusive-scan + stable scatter + -1 tail fill.
// One workgroup per chunk; the block recomputes its own global offset by
// summing counts[0..chunk-1] (<= 2336 L2-hot ints, ~18 loads/thread), writes
// its (n, by, bx) triples at offset + within-chunk popcount prefix, then
// writes -1 into its slack region of the output tail:
//   S_incl(i) = (i+1)*NBW - (e_i + c_i)   (inclusive slack prefix)
//   block i fills rows [TOTAL - S_incl, TOTAL - S_incl + (NBW - c_i))
// These regions are disjoint and exactly tile [grand_total, TOTAL), so every
// output row is written exactly once (harness poisons d_out each call).
__global__ __launch_bounds__(128) void scatter_kernel(const umask2* __restrict__ masks,
                                                      const int* __restrict__ counts,
                                                      int* __restrict__ out) {
    const int chunk = blockIdx.x;
    const int n  = chunk / NBH;
    const int by = chunk % NBH;
    const int tid  = threadIdx.x;
    const int lane = tid & 63;
    const int wave = tid >> 6;

    __shared__ int wsum[2];

    // global exclusive prefix of counts
    int partial = 0;
    for (int i = tid; i < chunk; i += 128) partial += counts[i];
    #pragma unroll
    for (int off = 32; off > 0; off >>= 1) partial += __shfl_down(partial, off, 64);
    if (lane == 0) wsum[wave] = partial;

    const umask2 m = masks[chunk];        // broadcast load, L2-hot
    __syncthreads();
    const int e = wsum[0] + wsum[1];
    const int c = __popcll(m.x) + __popcll(m.y);

    // stable scatter of active triples
    if (tid < NBW) {
        int f, prefix;
        if (wave == 0) {                  // bx 0..63 (wave-uniform branch)
            f = (int)((m.x >> tid) & 1ull);
            prefix = __popcll(m.x & ((1ull << tid) - 1ull));
        } else {                          // bx 64..72
            const int t = tid - 64;
            f = (int)((m.y >> t) & 1ull);
            prefix = __popcll(m.x) + __popcll(m.y & ((1ull << t) - 1ull));
        }
        if (f) {
            const int pos = e + prefix;
            out[3 * pos + 0] = n;
            out[3 * pos + 1] = by;
            out[3 * pos + 2] = tid;
        }
    }

    // -1 slack fill (zero iterations when all 73 blocks in this row are active)
    const int slack = NBW - c;
    if (slack > 0) {
        const int s_incl = (chunk + 1) * NBW - (e + c);
        const int base3 = 3 * (TOTAL - s_incl);
        const int n3 = 3 * slack;
        for (int i = tid; i < n3; i += 128) out[base3 + i] = -1;
    }
}

// ---------------------------------------------------------------------------
extern "C" void kernel_launch(void* const* d_in, const int* in_sizes, int n_in,
                              void* d_out, int out_size, void* d_ws, size_t ws_size,
                              hipStream_t stream) {
    const float* mask = (const float*)d_in[0];
    int* out = (int*)d_out;

    // workspace layout: [masks: 2336 x 16B][counts: 2336 x 4B]
    umask2* masks = (umask2*)d_ws;
    int* counts = (int*)(masks + NCHUNK);

    pool_kernel<<<NCHUNK, 256, 0, stream>>>(mask, masks, counts);
    scatter_kernel<<<NCHUNK, 128, 0, stream>>>(masks, counts, out);
}

// Round 4
// 190.770 us; speedup vs baseline: 1.0641x; 1.0002x over previous
//
#include <hip/hip_runtime.h>

// Problem constants (mirrors reference)
#define NI    32              // batch
#define HH    1024
#define WW    1024
#define BHW   16              // pool window
#define BS    14              // block stride
#define NBH   73              // block count h
#define NBW   73              // block count w
#define NCHUNK (NI * NBH)     // 2336 block-rows
#define TOTAL  (NI * NBH * NBW) // 170528

struct umask2 { unsigned long long x, y; };

__device__ __forceinline__ float4 max4(float4 a, float4 b) {
    return make_float4(fmaxf(a.x, b.x), fmaxf(a.y, b.y),
                       fmaxf(a.z, b.z), fmaxf(a.w, b.w));
}

// ---------------------------------------------------------------------------
// Kernel 1: one workgroup per (n, by) block-row.
// Window rows are [by*14-1, by*14+15). Only by==0 clips (row -1); upper edge
// never does (max row = 1022). So: block-uniform start rs = max(r0,0),
// 15 unconditional rows + 1 row predicated on by>0. No per-row clamp ->
// clean constant-stride load stream, all loads independent.
__global__ __launch_bounds__(256, 4) void pool_kernel(const float* __restrict__ mask,
                                                      umask2* __restrict__ masks,
                                                      int* __restrict__ counts) {
    const int chunk = blockIdx.x;         // n*NBH + by
    const int n  = chunk / NBH;
    const int by = chunk % NBH;
    const int tid = threadIdx.x;

    __shared__ float colmax[WW];
    __shared__ unsigned long long sm0, sm1;

    const int r0 = by * BS - 1;           // padded window start (pad=1)
    const int rs = max(r0, 0);            // block-uniform
    const float* p = mask + (size_t)n * HH * WW + (size_t)rs * WW + tid * 4;

    float4 m = *(const float4*)p;
    #pragma unroll
    for (int dr = 1; dr < 15; ++dr)
        m = max4(m, *(const float4*)(p + (size_t)dr * WW));
    if (by > 0)                           // block-uniform predicate: 16th row
        m = max4(m, *(const float4*)(p + (size_t)15 * WW));

    const int c = tid * 4;
    colmax[c + 0] = m.x;
    colmax[c + 1] = m.y;
    colmax[c + 2] = m.z;
    colmax[c + 3] = m.w;
    __syncthreads();

    int f = 0;
    if (tid < NBW) {
        const int c0 = tid * BS - 1;
        float mx = colmax[max(c0, 0)];    // dc=0 clamped; dc>=1 always >= 0
        #pragma unroll
        for (int dc = 1; dc < BHW; ++dc) mx = fmaxf(mx, colmax[c0 + dc]);
        f = (mx > 0.9f) ? 1 : 0;
    }
    const unsigned long long b = __ballot(f);
    const int wave = tid >> 6;
    const int lane = tid & 63;
    if (wave == 0 && lane == 0) sm0 = b;  // bits for bx 0..63
    if (wave == 1 && lane == 0) sm1 = b;  // bits for bx 64..72
    __syncthreads();
    if (tid == 0) {
        umask2 mm; mm.x = sm0; mm.y = sm1;
        masks[chunk] = mm;
        counts[chunk] = __popcll(sm0) + __popcll(sm1);
    }
}

// ---------------------------------------------------------------------------
// Kernel 2: fused exclusive-scan + stable scatter + -1 tail fill.
// One workgroup per chunk; the block recomputes its own global offset by
// summing counts[0..chunk-1] (<= 2336 L2-hot ints), writes its (n, by, bx)
// triples at offset + within-chunk popcount prefix, then fills its disjoint
// slack region of the -1 tail:
//   S_incl(i) = (i+1)*NBW - (e_i + c_i); block i fills
//   rows [TOTAL - S_incl, TOTAL - S_incl + (NBW - c_i))  — exact tiling of
//   [grand_total, TOTAL), every output row written exactly once.
__global__ __launch_bounds__(128) void scatter_kernel(const umask2* __restrict__ masks,
                                                      const int* __restrict__ counts,
                                                      int* __restrict__ out) {
    const int chunk = blockIdx.x;
    const int n  = chunk / NBH;
    const int by = chunk % NBH;
    const int tid  = threadIdx.x;
    const int lane = tid & 63;
    const int wave = tid >> 6;

    __shared__ int wsum[2];

    // global exclusive prefix of counts
    int partial = 0;
    for (int i = tid; i < chunk; i += 128) partial += counts[i];
    #pragma unroll
    for (int off = 32; off > 0; off >>= 1) partial += __shfl_down(partial, off, 64);
    if (lane == 0) wsum[wave] = partial;

    const umask2 m = masks[chunk];        // broadcast load, L2-hot
    __syncthreads();
    const int e = wsum[0] + wsum[1];
    const int c = __popcll(m.x) + __popcll(m.y);

    // stable scatter of active triples
    if (tid < NBW) {
        int f, prefix;
        if (wave == 0) {                  // bx 0..63 (wave-uniform branch)
            f = (int)((m.x >> tid) & 1ull);
            prefix = __popcll(m.x & ((1ull << tid) - 1ull));
        } else {                          // bx 64..72
            const int t = tid - 64;
            f = (int)((m.y >> t) & 1ull);
            prefix = __popcll(m.x) + __popcll(m.y & ((1ull << t) - 1ull));
        }
        if (f) {
            const int pos = e + prefix;
            out[3 * pos + 0] = n;
            out[3 * pos + 1] = by;
            out[3 * pos + 2] = tid;
        }
    }

    // -1 slack fill (zero iterations when all 73 blocks in this row are active)
    const int slack = NBW - c;
    if (slack > 0) {
        const int s_incl = (chunk + 1) * NBW - (e + c);
        const int base3 = 3 * (TOTAL - s_incl);
        const int n3 = 3 * slack;
        for (int i = tid; i < n3; i += 128) out[base3 + i] = -1;
    }
}

// ---------------------------------------------------------------------------
extern "C" void kernel_launch(void* const* d_in, const int* in_sizes, int n_in,
                              void* d_out, int out_size, void* d_ws, size_t ws_size,
                              hipStream_t stream) {
    const float* mask = (const float*)d_in[0];
    int* out = (int*)d_out;

    // workspace layout: [masks: 2336 x 16B][counts: 2336 x 4B]
    umask2* masks = (umask2*)d_ws;
    int* counts = (int*)(masks + NCHUNK);

    pool_kernel<<<NCHUNK, 256, 0, stream>>>(mask, masks, counts);
    scatter_kernel<<<NCHUNK, 128, 0, stream>>>(masks, counts, out);
}

// Round 5
// 177.860 us; speedup vs baseline: 1.1414x; 1.0726x over previous
//
#include <hip/hip_runtime.h>

// Problem constants (mirrors reference)
#define NI    32              // batch
#define HH    1024
#define WW    1024
#define BHW   16              // pool window
#define BS    14              // block stride
#define NBH   73              // block count h
#define NBW   73              // block count w
#define NCHUNK (NI * NBH)     // 2336 block-rows
#define TOTAL  (NI * NBH * NBW) // 170528

struct umask2 { unsigned long long x, y; };

__device__ __forceinline__ float4 max4(float4 a, float4 b) {
    return make_float4(fmaxf(a.x, b.x), fmaxf(a.y, b.y),
                       fmaxf(a.z, b.z), fmaxf(a.w, b.w));
}

// ---------------------------------------------------------------------------
// Kernel 1: one workgroup per (n, by) block-row, with probabilistic early exit.
//
// Flags are booleans of a monotone max: once every one of the 73 windows
// provably contains an element > 0.9, remaining rows cannot change anything.
// Stream rows in pairs; after each pair, per-lane "running colmax4 > 0.9"
// ballots give a 256-bit map (1 bit = 4 cols). For window bx (cols
// [14bx-1, 14bx+14]) test only ballot bits FULLY INSIDE the window:
//   lo = (14bx+2)>>2, hi = (14bx+11)>>2   (3-4 bits, >=12 interior cols)
// A set bit there proves window-max > 0.9 (no false positives). If all 73
// prove out, emit mask=all-ones/count=73 exactly and stop reading. Uniform
// data exits after ~4-6 of 16 rows (~3x fewer HBM bytes). The no-exit path
// (P ~ 1e-7 per chunk) falls through to the exact colmax + horizontal pass.
__global__ __launch_bounds__(256, 4) void pool_kernel(const float* __restrict__ mask,
                                                      umask2* __restrict__ masks,
                                                      int* __restrict__ counts) {
    const int chunk = blockIdx.x;         // n*NBH + by
    const int n  = chunk / NBH;
    const int by = chunk % NBH;
    const int tid  = threadIdx.x;
    const int lane = tid & 63;
    const int wave = tid >> 6;

    __shared__ float colmax[WW];
    __shared__ unsigned long long wb[4];
    __shared__ int sdone[4];
    __shared__ unsigned long long sm0, sm1;

    const int r0 = by * BS - 1;           // padded window start (pad=1)
    const int rs = max(r0, 0);            // only by==0 clips; top edge never does
    const int nr = (by > 0) ? 16 : 15;    // valid rows in window
    const float* p = mask + (size_t)n * HH * WW + (size_t)rs * WW + tid * 4;

    float4 m = make_float4(-1e30f, -1e30f, -1e30f, -1e30f);
    bool done = false;

    for (int k = 0; k < 8 && !done; ++k) {
        const int r1 = 2 * k, r2 = 2 * k + 1;
        m = max4(m, *(const float4*)(p + (size_t)r1 * WW));
        if (r2 < nr)                      // block-uniform predicate
            m = max4(m, *(const float4*)(p + (size_t)r2 * WW));

        // conservative all-windows-hit test on running colmax
        const float mm = fmaxf(fmaxf(m.x, m.y), fmaxf(m.z, m.w));
        const unsigned long long bal = __ballot(mm > 0.9f);
        if (lane == 0) wb[wave] = bal;
        __syncthreads();

        bool whit = true;
        if (tid < NBW) {
            const int c0 = tid * BS;
            const int lo = (c0 + 2) >> 2;         // first bit fully inside window
            const int hi = (c0 + 11) >> 2;        // last bit fully inside window
            const int w0 = lo >> 6, sh = lo & 63;
            unsigned long long bits = wb[w0] >> sh;
            if (w0 < 3 && sh) bits |= wb[w0 + 1] << (64 - sh);
            const int nb = hi - lo + 1;           // 3 or 4
            whit = (bits & ((1ull << nb) - 1ull)) != 0ull;
        }
        const unsigned long long miss = __ballot(!whit);  // tid>=73 -> whit=true
        if (lane == 0) sdone[wave] = (miss == 0ull);
        __syncthreads();
        done = (sdone[0] & sdone[1] & sdone[2] & sdone[3]) != 0;
        // no extra sync needed: wb/sdone writes of iter k+1 happen after the
        // syncthreads above, and all reads of iter k precede it.
        __syncthreads();
    }

    if (done) {                           // exact: every window proved > 0.9
        if (tid == 0) {
            umask2 mmk; mmk.x = ~0ull; mmk.y = (1ull << (NBW - 64)) - 1ull;
            masks[chunk] = mmk;
            counts[chunk] = NBW;
        }
        return;                           // block-uniform
    }

    // exact fallback (all 16 rows accumulated in m)
    const int c = tid * 4;
    colmax[c + 0] = m.x;
    colmax[c + 1] = m.y;
    colmax[c + 2] = m.z;
    colmax[c + 3] = m.w;
    __syncthreads();

    int f = 0;
    if (tid < NBW) {
        const int c0 = tid * BS - 1;
        float mx = colmax[max(c0, 0)];    // dc=0 clamped; dc>=1 always >= 0
        #pragma unroll
        for (int dc = 1; dc < BHW; ++dc) mx = fmaxf(mx, colmax[c0 + dc]);
        f = (mx > 0.9f) ? 1 : 0;
    }
    const unsigned long long b = __ballot(f);
    if (wave == 0 && lane == 0) sm0 = b;  // bits for bx 0..63
    if (wave == 1 && lane == 0) sm1 = b;  // bits for bx 64..72
    __syncthreads();
    if (tid == 0) {
        umask2 mm2; mm2.x = sm0; mm2.y = sm1;
        masks[chunk] = mm2;
        counts[chunk] = __popcll(sm0) + __popcll(sm1);
    }
}

// ---------------------------------------------------------------------------
// Kernel 2: fused exclusive-scan + stable scatter + -1 tail fill (unchanged).
// Block recomputes its global offset by summing counts[0..chunk-1] (L2-hot),
// scatters (n, by, bx) triples, then fills its disjoint slack region:
//   S_incl(i) = (i+1)*NBW - (e_i + c_i); block i fills
//   rows [TOTAL - S_incl, TOTAL - S_incl + (NBW - c_i))  — exact tiling of
//   [grand_total, TOTAL); every output row written exactly once.
__global__ __launch_bounds__(128) void scatter_kernel(const umask2* __restrict__ masks,
                                                      const int* __restrict__ counts,
                                                      int* __restrict__ out) {
    const int chunk = blockIdx.x;
    const int n  = chunk / NBH;
    const int by = chunk % NBH;
    const int tid  = threadIdx.x;
    const int lane = tid & 63;
    const int wave = tid >> 6;

    __shared__ int wsum[2];

    // global exclusive prefix of counts
    int partial = 0;
    for (int i = tid; i < chunk; i += 128) partial += counts[i];
    #pragma unroll
    for (int off = 32; off > 0; off >>= 1) partial += __shfl_down(partial, off, 64);
    if (lane == 0) wsum[wave] = partial;

    const umask2 m = masks[chunk];        // broadcast load, L2-hot
    __syncthreads();
    const int e = wsum[0] + wsum[1];
    const int c = __popcll(m.x) + __popcll(m.y);

    // stable scatter of active triples
    if (tid < NBW) {
        int f, prefix;
        if (wave == 0) {                  // bx 0..63 (wave-uniform branch)
            f = (int)((m.x >> tid) & 1ull);
            prefix = __popcll(m.x & ((1ull << tid) - 1ull));
        } else {                          // bx 64..72
            const int t = tid - 64;
            f = (int)((m.y >> t) & 1ull);
            prefix = __popcll(m.x) + __popcll(m.y & ((1ull << t) - 1ull));
        }
        if (f) {
            const int pos = e + prefix;
            out[3 * pos + 0] = n;
            out[3 * pos + 1] = by;
            out[3 * pos + 2] = tid;
        }
    }

    // -1 slack fill (zero iterations when all 73 blocks in this row are active)
    const int slack = NBW - c;
    if (slack > 0) {
        const int s_incl = (chunk + 1) * NBW - (e + c);
        const int base3 = 3 * (TOTAL - s_incl);
        const int n3 = 3 * slack;
        for (int i = tid; i < n3; i += 128) out[base3 + i] = -1;
    }
}

// ---------------------------------------------------------------------------
extern "C" void kernel_launch(void* const* d_in, const int* in_sizes, int n_in,
                              void* d_out, int out_size, void* d_ws, size_t ws_size,
                              hipStream_t stream) {
    const float* mask = (const float*)d_in[0];
    int* out = (int*)d_out;

    // workspace layout: [masks: 2336 x 16B][counts: 2336 x 4B]
    umask2* masks = (umask2*)d_ws;
    int* counts = (int*)(masks + NCHUNK);

    pool_kernel<<<NCHUNK, 256, 0, stream>>>(mask, masks, counts);
    scatter_kernel<<<NCHUNK, 128, 0, stream>>>(masks, counts, out);
}